// Round 7
// baseline (208.931 us; speedup 1.0000x reference)
//
#include <hip/hip_runtime.h>
#include <math.h>

typedef __bf16 bf16_t;
typedef bf16_t bf16x8 __attribute__((ext_vector_type(8)));
typedef bf16_t bf16x4 __attribute__((ext_vector_type(4)));
typedef float f32x4 __attribute__((ext_vector_type(4)));

constexpr int S_ = 2048;
constexpr float SCALE = 0.125f;  // 1/sqrt(64)

#define MFMA_B16(a, b, c) __builtin_amdgcn_mfma_f32_16x16x32_bf16(a, b, c, 0, 0, 0)

// s_waitcnt immediates (gfx9 encoding): vmcnt(0) only / lgkmcnt(0) only
#define WAIT_VM0()   __builtin_amdgcn_s_waitcnt(0x0F70)
#define WAIT_LGKM0() __builtin_amdgcn_s_waitcnt(0xC07F)
#define BARRIER()    __builtin_amdgcn_s_barrier()

typedef __attribute__((address_space(1))) const void* as1_cvp;
typedef __attribute__((address_space(3))) void* as3_vp;

__device__ __forceinline__ void gl2lds16(const void* g, void* l)
{
    __builtin_amdgcn_global_load_lds((as1_cvp)g, (as3_vp)l, 16, 0, 0);
}

// ---------------------------------------------------------------------------
// prep: cast x -> bf16 (blocks 0..1023), transpose-cast 4 weights (1024..2047),
// zero vsp (block 2048)
// ---------------------------------------------------------------------------
__global__ __launch_bounds__(256) void prep(const float* __restrict__ x,
                                            const float* __restrict__ Wq,
                                            const float* __restrict__ Wk,
                                            const float* __restrict__ Wv,
                                            const float* __restrict__ Wo,
                                            bf16_t* __restrict__ xb,
                                            bf16_t* __restrict__ Wqt,
                                            bf16_t* __restrict__ Wkt,
                                            bf16_t* __restrict__ Wvt,
                                            bf16_t* __restrict__ Wot,
                                            float* __restrict__ vsp)
{
    __shared__ float T[64][65];
    const int blk = blockIdx.x;
    const int tid = threadIdx.x;
    if (blk < 1024) {
#pragma unroll
        for (int u = 0; u < 4; ++u) {
            const int g = blk * 1024 + u * 256 + tid;
            const float4 v = ((const float4*)x)[g];
            bf16x4 o;
            o[0] = (bf16_t)v.x; o[1] = (bf16_t)v.y;
            o[2] = (bf16_t)v.z; o[3] = (bf16_t)v.w;
            *(bf16x4*)&xb[(size_t)g * 4] = o;
        }
    } else if (blk < 2048) {
        const int rem = blk - 1024;
        const int wsel = rem >> 8, t = rem & 255;
        const float* src = (wsel == 0) ? Wq : (wsel == 1) ? Wk : (wsel == 2) ? Wv : Wo;
        bf16_t* dst = (wsel == 0) ? Wqt : (wsel == 1) ? Wkt : (wsel == 2) ? Wvt : Wot;
        const int k0 = (t >> 4) * 64, n0 = (t & 15) * 64;
        const int rr = tid >> 4, c4 = (tid & 15) * 4;
#pragma unroll
        for (int u = 0; u < 4; ++u) {
            const float4 v = *(const float4*)&src[(size_t)(k0 + u * 16 + rr) * 1024 + n0 + c4];
            T[u * 16 + rr][c4 + 0] = v.x; T[u * 16 + rr][c4 + 1] = v.y;
            T[u * 16 + rr][c4 + 2] = v.z; T[u * 16 + rr][c4 + 3] = v.w;
        }
        __syncthreads();
#pragma unroll
        for (int u = 0; u < 4; ++u) {
            bf16x4 o;
#pragma unroll
            for (int e = 0; e < 4; ++e) o[e] = (bf16_t)T[c4 + e][u * 16 + rr];
            *(bf16x4*)&dst[(size_t)(n0 + u * 16 + rr) * 1024 + k0 + c4] = o;
        }
    } else {
#pragma unroll
        for (int u = 0; u < 8; ++u) vsp[u * 256 + tid] = 0.f;
    }
}

// ---------------------------------------------------------------------------
// bf16 MFMA GEMM, software-pipelined: double-buffered LDS, raw s_barrier +
// manual vmcnt so next tile's global_load_lds stays in flight across the
// barrier (loads fly during compute of current tile).
// ---------------------------------------------------------------------------
template <int MODE>
__device__ __forceinline__ void mfma_gemm_body(const bf16_t* __restrict__ A,
                                               const bf16_t* __restrict__ Bt,
                                               void* __restrict__ dst,
                                               float* __restrict__ vsum_out,
                                               int m0, int n0)
{
    __shared__ bf16_t As[8192];  // dbuf: [2][128][32]
    __shared__ bf16_t Bs[8192];

    const int tid = threadIdx.x;
    const int lane = tid & 63, wid = tid >> 6;
    const int l15 = lane & 15, quad = lane >> 4;
    const int wm = (wid & 1) * 64, wn = (wid >> 1) * 64;

    const int srow = wid * 32 + (lane >> 2);
    const int scg8 = (lane & 3) * 8;
    const bf16_t* Ag0 = A  + (size_t)(m0 + srow) * 1024 + scg8;
    const bf16_t* Ag1 = A  + (size_t)(m0 + srow + 16) * 1024 + scg8;
    const bf16_t* Bg0 = Bt + (size_t)(n0 + srow) * 1024 + scg8;
    const bf16_t* Bg1 = Bt + (size_t)(n0 + srow + 16) * 1024 + scg8;

    f32x4 acc[4][4];
#pragma unroll
    for (int i = 0; i < 4; ++i)
#pragma unroll
        for (int j = 0; j < 4; ++j) acc[i][j] = (f32x4){0.f, 0.f, 0.f, 0.f};

    // prologue: stage tile 0 into buffer 0
    gl2lds16(Ag0, As + (wid * 2 + 0) * 512);
    gl2lds16(Ag1, As + (wid * 2 + 1) * 512);
    gl2lds16(Bg0, Bs + (wid * 2 + 0) * 512);
    gl2lds16(Bg1, Bs + (wid * 2 + 1) * 512);

    for (int it = 0; it < 32; ++it) {
        WAIT_VM0();   // current tile's loads complete (per-wave)
        BARRIER();    // all waves: tile ready AND prev compute done
        const int cur = it & 1, nxt = cur ^ 1;
        if (it + 1 < 32) {
            const int k0 = (it + 1) * 32;
            gl2lds16(Ag0 + k0, As + nxt * 4096 + (wid * 2 + 0) * 512);
            gl2lds16(Ag1 + k0, As + nxt * 4096 + (wid * 2 + 1) * 512);
            gl2lds16(Bg0 + k0, Bs + nxt * 4096 + (wid * 2 + 0) * 512);
            gl2lds16(Bg1 + k0, Bs + nxt * 4096 + (wid * 2 + 1) * 512);
        }
        bf16x8 af[4], bfr[4];
#pragma unroll
        for (int mt = 0; mt < 4; ++mt)
            af[mt] = *(const bf16x8*)&As[cur * 4096 + (wm + mt * 16 + l15) * 32 + quad * 8];
#pragma unroll
        for (int nt = 0; nt < 4; ++nt)
            bfr[nt] = *(const bf16x8*)&Bs[cur * 4096 + (wn + nt * 16 + l15) * 32 + quad * 8];
#pragma unroll
        for (int mt = 0; mt < 4; ++mt)
#pragma unroll
            for (int nt = 0; nt < 4; ++nt)
                acc[mt][nt] = MFMA_B16(bfr[nt], af[mt], acc[mt][nt]);  // lane=m, regs=n
    }

#pragma unroll
    for (int mt = 0; mt < 4; ++mt) {
        const int m = m0 + wm + mt * 16 + l15;
#pragma unroll
        for (int nt = 0; nt < 4; ++nt) {
            const int nb = n0 + wn + nt * 16 + quad * 4;
            if (MODE == 0) {
                *(f32x4*)&((float*)dst)[(size_t)m * 1024 + nb] = acc[mt][nt];
            } else {
                const int bb = m >> 11, s = m & 2047;
                const int hh = nb >> 6, d = nb & 63;
                bf16x4 o;
#pragma unroll
                for (int u = 0; u < 4; ++u) o[u] = (bf16_t)acc[mt][nt][u];
                *(bf16x4*)&((bf16_t*)dst)[((size_t)(bb * 16 + hh) * 2048 + s) * 64 + d] = o;
            }
        }
    }

    if (MODE == 1 && vsum_out != nullptr) {
        const int bb = m0 >> 11;
#pragma unroll
        for (int nt = 0; nt < 4; ++nt) {
            f32x4 p = acc[0][nt];
#pragma unroll
            for (int mt = 1; mt < 4; ++mt) {
                p[0] += acc[mt][nt][0]; p[1] += acc[mt][nt][1];
                p[2] += acc[mt][nt][2]; p[3] += acc[mt][nt][3];
            }
#pragma unroll
            for (int st = 1; st < 16; st <<= 1) {
                p[0] += __shfl_xor(p[0], st);
                p[1] += __shfl_xor(p[1], st);
                p[2] += __shfl_xor(p[2], st);
                p[3] += __shfl_xor(p[3], st);
            }
            if (l15 == 0) {
                const int nI = n0 + wn + nt * 16 + quad * 4;
                float* vp = &vsum_out[(bb * 16 + (nI >> 6)) * 64 + (nI & 63)];
                atomicAdd(vp + 0, p[0]);
                atomicAdd(vp + 1, p[1]);
                atomicAdd(vp + 2, p[2]);
                atomicAdd(vp + 3, p[3]);
            }
        }
    }
}

__global__ __launch_bounds__(256) void gemm_qkv_mfma(const bf16_t* __restrict__ xb,
                                                     const bf16_t* __restrict__ Wqt,
                                                     const bf16_t* __restrict__ Wkt,
                                                     const bf16_t* __restrict__ Wvt,
                                                     bf16_t* Qh, bf16_t* Kh, bf16_t* Vh,
                                                     float* vsp)
{
    const bf16_t* Bt = (blockIdx.z == 0) ? Wqt : (blockIdx.z == 1) ? Wkt : Wvt;
    bf16_t* dst = (blockIdx.z == 0) ? Qh : (blockIdx.z == 1) ? Kh : Vh;
    float* vs = (blockIdx.z == 2) ? vsp : nullptr;
    mfma_gemm_body<1>(xb, Bt, dst, vs, blockIdx.y * 128, blockIdx.x * 128);
}

__global__ __launch_bounds__(256) void gemm_out_mfma(const bf16_t* __restrict__ attn,
                                                     const bf16_t* __restrict__ Wot,
                                                     float* __restrict__ out)
{
    mfma_gemm_body<0>(attn, Wot, out, nullptr, blockIdx.y * 128, blockIdx.x * 128);
}

// ---------------------------------------------------------------------------
// Fused rowmax + band attention, v3 (software-pipelined phase 1).
// 512 blocks, XCD-swizzled (bh % 8 == blockIdx % 8). Block = 128 q-rows.
// Phase 1: rowmax, 16 chunks of 128 j, double-buffered K with raw barrier +
// vmcnt (loads in flight across barrier). Q staged into buf0, fragments
// hoisted to registers, then buf0 recycled. Phase 2: 6x64-j band chunks
// (__syncthreads flow, as round 6).
// ---------------------------------------------------------------------------
__global__ __launch_bounds__(256, 4) void attn_fused(const bf16_t* __restrict__ Qh,
                                                     const bf16_t* __restrict__ Kh,
                                                     const bf16_t* __restrict__ Vh,
                                                     const float* __restrict__ vsp,
                                                     bf16_t* __restrict__ attn)
{
    __shared__ bf16_t pool[17920];  // p1: Kdbuf [2][128][64]; p2: Ks2+Vt+Ws
    __shared__ float msh[4][8][16]; // phase-1 partial maxima; zsh aliases it

    bf16_t* Ks2 = pool;             // [2][64][32]  (4096)
    bf16_t* Vt  = pool + 4096;      // [64][72]     (4608) [d][j]
    bf16_t* Ws  = pool + 8704;      // [128][72]    (9216) [i][j]
    float (*zsh)[32] = (float(*)[32])msh;

    const int tid = threadIdx.x;
    const int lane = tid & 63, wid = tid >> 6;
    const int l15 = lane & 15, quad = lane >> 4;

    const int f = blockIdx.x;
    const int seq = f >> 3;
    const int bh = (f & 7) + 8 * (seq >> 4);   // XCD-locality
    const int i0 = (seq & 15) * 128;
    const int b = bh >> 4, h = bh & 15;
    const bf16_t* Qb = Qh + (size_t)bh * 131072;
    const bf16_t* Kb = Kh + (size_t)bh * 131072;
    const bf16_t* Vb = Vh + (size_t)bh * 131072;

    // ---- stage Q [2][128][32] into buf0, K chunk 0 into buf1 ----
#pragma unroll
    for (int c = 0; c < 4; ++c) {
        const int g = wid * 4 + c;
        const int half = g >> 3;
        const int row = (g & 7) * 16 + (lane >> 2);
        gl2lds16(Qb + (size_t)(i0 + row) * 64 + half * 32 + (lane & 3) * 8,
                 pool + g * 512);
        gl2lds16(Kb + (size_t)row * 64 + half * 32 + (lane & 3) * 8,
                 pool + 8192 + g * 512);
    }
    WAIT_VM0();
    BARRIER();

    // hoist Q fragments (dual-use: phase-1 B-operand, phase-2 A-operand)
    bf16x8 af[8][2];
#pragma unroll
    for (int mt = 0; mt < 8; ++mt)
#pragma unroll
        for (int ks = 0; ks < 2; ++ks)
            af[mt][ks] = *(const bf16x8*)&pool[ks * 4096 + (mt * 16 + l15) * 32 + quad * 8];
    WAIT_LGKM0();  // af reads landed before any wave overwrites buf0

    // ---- phase 1: rowmax, 16 chunks of 128 j, dbuf pipeline ----
    // chunk jc lives in buffer ((jc+1)&1); chunk 0 pre-staged in buf1.
    float rmax[8];
#pragma unroll
    for (int mt = 0; mt < 8; ++mt) rmax[mt] = -3.0e38f;

    for (int jc = 0; jc < 16; ++jc) {
        if (jc) WAIT_VM0();   // chunk jc's loads (issued last iter) done
        BARRIER();            // all waves past prev compute -> buf reusable
        if (jc + 1 < 16) {
            bf16_t* nb = pool + (jc & 1) * 8192;
#pragma unroll
            for (int c = 0; c < 4; ++c) {
                const int g = wid * 4 + c;
                const int half = g >> 3;
                const int row = (g & 7) * 16 + (lane >> 2);
                gl2lds16(Kb + (size_t)((jc + 1) * 128 + row) * 64 + half * 32 + (lane & 3) * 8,
                         nb + g * 512);
            }
        }
        const bf16_t* cb = pool + (((jc + 1) & 1)) * 8192;
#pragma unroll
        for (int ntl = 0; ntl < 2; ++ntl) {
            const int jt = wid * 2 + ntl;
            const bf16x8 b0 = *(const bf16x8*)&cb[(jt * 16 + l15) * 32 + quad * 8];
            const bf16x8 b1 = *(const bf16x8*)&cb[4096 + (jt * 16 + l15) * 32 + quad * 8];
#pragma unroll
            for (int mt = 0; mt < 8; ++mt) {
                f32x4 t = (f32x4){0.f, 0.f, 0.f, 0.f};
                t = MFMA_B16(b0, af[mt][0], t);   // lane = i, regs = j
                t = MFMA_B16(b1, af[mt][1], t);
                rmax[mt] = fmaxf(rmax[mt], fmaxf(fmaxf(t[0], t[1]), fmaxf(t[2], t[3])));
            }
        }
    }
#pragma unroll
    for (int mt = 0; mt < 8; ++mt) {
        float v = rmax[mt];
        v = fmaxf(v, __shfl_xor(v, 16));
        v = fmaxf(v, __shfl_xor(v, 32));
        if (quad == 0) msh[wid][mt][l15] = v;
    }
    __syncthreads();  // msh visible; phase-1 pool reads done

    float mreg[2][4];
#pragma unroll
    for (int t = 0; t < 2; ++t)
#pragma unroll
        for (int r = 0; r < 4; ++r) {
            const int mt = wid * 2 + t;
            const int il = quad * 4 + r;
            mreg[t][r] = SCALE * fmaxf(fmaxf(msh[0][mt][il], msh[1][mt][il]),
                                       fmaxf(msh[2][mt][il], msh[3][mt][il]));
        }

    f32x4 vsd4[4];
#pragma unroll
    for (int dt = 0; dt < 4; ++dt)
        vsd4[dt] = *(const f32x4*)&vsp[bh * 64 + dt * 16 + quad * 4];

    f32x4 accO[2][4];
#pragma unroll
    for (int t = 0; t < 2; ++t)
#pragma unroll
        for (int dt = 0; dt < 4; ++dt) accO[t][dt] = (f32x4){0.f, 0.f, 0.f, 0.f};
    float zp[2][4] = {{0.f, 0.f, 0.f, 0.f}, {0.f, 0.f, 0.f, 0.f}};

    // ---- phase 2: 6 band chunks of 64 j ----
    for (int cb2 = 0; cb2 < 6; ++cb2) {
        const int jb = i0 - 128 + cb2 * 64;
        if (jb < 0 || jb >= S_) continue;  // block-uniform

        __syncthreads();
#pragma unroll
        for (int c = 0; c < 2; ++c) {
            const int g = wid * 2 + c;
            const int half = g >> 2;
            const int row = (g & 3) * 16 + (lane >> 2);
            gl2lds16(Kb + (size_t)(jb + row) * 64 + half * 32 + (lane & 3) * 8,
                     Ks2 + g * 512);
        }
        {
            const bf16x8 v0 = *(const bf16x8*)&Vb[(size_t)(jb + lane) * 64 + wid * 16];
            const bf16x8 v1 = *(const bf16x8*)&Vb[(size_t)(jb + lane) * 64 + wid * 16 + 8];
#pragma unroll
            for (int e = 0; e < 8; ++e) {
                Vt[(wid * 16 + e) * 72 + lane] = v0[e];
                Vt[(wid * 16 + 8 + e) * 72 + lane] = v1[e];
            }
        }
        __syncthreads();

#pragma unroll
        for (int t = 0; t < 2; ++t) {
            const int mt = wid * 2 + t;
#pragma unroll
            for (int jt4 = 0; jt4 < 4; ++jt4) {
                const bf16x8 k0 = *(const bf16x8*)&Ks2[(jt4 * 16 + l15) * 32 + quad * 8];
                const bf16x8 k1 = *(const bf16x8*)&Ks2[2048 + (jt4 * 16 + l15) * 32 + quad * 8];
                f32x4 sc = (f32x4){0.f, 0.f, 0.f, 0.f};
                sc = MFMA_B16(af[mt][0], k0, sc);   // lane = j, regs = i
                sc = MFMA_B16(af[mt][1], k1, sc);
#pragma unroll
                for (int r = 0; r < 4; ++r) {
                    const int ig = i0 + mt * 16 + quad * 4 + r;
                    const int jg = jb + jt4 * 16 + l15;
                    const int dd = jg - ig;
                    const bool ok = (dd >= -128) && (dd <= 127);
                    const float e1 = __expf(sc[r] * SCALE - mreg[t][r]);
                    const float wv = ok ? (__expf(e1) - 1.0f) : 0.0f;
                    const bf16_t wb = (bf16_t)wv;
                    zp[t][r] += (float)wb;
                    Ws[(mt * 16 + quad * 4 + r) * 72 + jt4 * 16 + l15] = wb;
                }
            }
        }
        __syncthreads();

#pragma unroll
        for (int ks = 0; ks < 2; ++ks) {
            bf16x8 bv[4];
#pragma unroll
            for (int dt = 0; dt < 4; ++dt)
                bv[dt] = *(const bf16x8*)&Vt[(dt * 16 + l15) * 72 + ks * 32 + quad * 8];
#pragma unroll
            for (int t = 0; t < 2; ++t) {
                const int mt = wid * 2 + t;
                const bf16x8 aw = *(const bf16x8*)&Ws[(mt * 16 + l15) * 72 + ks * 32 + quad * 8];
#pragma unroll
                for (int dt = 0; dt < 4; ++dt)
                    accO[t][dt] = MFMA_B16(bv[dt], aw, accO[t][dt]);
            }
        }
    }

    // Z reduce + redistribute (zsh aliases msh; all msh reads done long ago)
#pragma unroll
    for (int t = 0; t < 2; ++t)
#pragma unroll
        for (int r = 0; r < 4; ++r) {
            float z = zp[t][r];
            z += __shfl_xor(z, 1);
            z += __shfl_xor(z, 2);
            z += __shfl_xor(z, 4);
            z += __shfl_xor(z, 8);
            if (l15 == 0) zsh[wid][t * 16 + quad * 4 + r] = z + (float)S_;
        }
    __syncthreads();

#pragma unroll
    for (int t = 0; t < 2; ++t) {
        const float rz = 1.0f / zsh[wid][t * 16 + l15];
        const int irow = i0 + (wid * 2 + t) * 16 + l15;
#pragma unroll
        for (int dt = 0; dt < 4; ++dt) {
            bf16x4 o;
#pragma unroll
            for (int r = 0; r < 4; ++r)
                o[r] = (bf16_t)((accO[t][dt][r] + vsd4[dt][r]) * rz);
            *(bf16x4*)&attn[(size_t)(b * S_ + irow) * 1024 + h * 64 + dt * 16 + quad * 4] = o;
        }
    }
}

// ---------------------------------------------------------------------------
// Launch: 4 kernels
// ---------------------------------------------------------------------------
extern "C" void kernel_launch(void* const* d_in, const int* in_sizes, int n_in,
                              void* d_out, int out_size, void* d_ws, size_t ws_size,
                              hipStream_t stream)
{
    const float* x  = (const float*)d_in[0];
    const float* Wq = (const float*)d_in[1];
    const float* Wk = (const float*)d_in[2];
    const float* Wv = (const float*)d_in[3];
    const float* Wo = (const float*)d_in[4];
    float* out = (float*)d_out;

    char* ws = (char*)d_ws;
    bf16_t* xb   = (bf16_t*)(ws + 0);
    bf16_t* Wqt  = (bf16_t*)(ws + 8388608);
    bf16_t* Wkt  = (bf16_t*)(ws + 10485760);
    bf16_t* Wvt  = (bf16_t*)(ws + 12582912);
    bf16_t* Wot  = (bf16_t*)(ws + 14680064);
    bf16_t* Qh   = (bf16_t*)(ws + 16777216);   // [bh][s][64]
    bf16_t* Kh   = (bf16_t*)(ws + 25165824);
    bf16_t* Vh   = (bf16_t*)(ws + 33554432);
    bf16_t* attn = (bf16_t*)(ws + 41943040);   // [m][1024]
    float*  vsp  = (float*)(ws + 50331648);    // [bh][64] f32, zeroed by prep

    prep<<<2049, 256, 0, stream>>>(x, Wq, Wk, Wv, Wo, xb, Wqt, Wkt, Wvt, Wot, vsp);
    gemm_qkv_mfma<<<dim3(8, 32, 3), 256, 0, stream>>>(xb, Wqt, Wkt, Wvt, Qh, Kh, Vh, vsp);
    attn_fused<<<512, 256, 0, stream>>>(Qh, Kh, Vh, vsp, attn);
    gemm_out_mfma<<<dim3(8, 32), 256, 0, stream>>>(attn, Wot, out);
}

// Round 8
// 189.992 us; speedup vs baseline: 1.0997x; 1.0997x over previous
//
#include <hip/hip_runtime.h>
#include <math.h>

typedef __bf16 bf16_t;
typedef bf16_t bf16x8 __attribute__((ext_vector_type(8)));
typedef bf16_t bf16x4 __attribute__((ext_vector_type(4)));
typedef float f32x4 __attribute__((ext_vector_type(4)));

constexpr int S_ = 2048;
constexpr float SCALE = 0.125f;  // 1/sqrt(64)

#define MFMA_B16(a, b, c) __builtin_amdgcn_mfma_f32_16x16x32_bf16(a, b, c, 0, 0, 0)

// s_waitcnt immediates (gfx9 enc): [3:0]=vmcnt_lo, [6:4]=expcnt, [12:8]=lgkmcnt
#define WAIT_VM0() __builtin_amdgcn_s_waitcnt(0x0F70)  // vmcnt(0), others free
#define WAIT_VM4() __builtin_amdgcn_s_waitcnt(0x0F74)  // vmcnt(4), others free
#define WAIT_VM8() __builtin_amdgcn_s_waitcnt(0x0F78)  // vmcnt(8), others free
#define BARRIER()  __builtin_amdgcn_s_barrier()

typedef __attribute__((address_space(1))) const void* as1_cvp;
typedef __attribute__((address_space(3))) void* as3_vp;

__device__ __forceinline__ void gl2lds16(const void* g, void* l)
{
    __builtin_amdgcn_global_load_lds((as1_cvp)g, (as3_vp)l, 16, 0, 0);
}

// ---------------------------------------------------------------------------
// prep: cast x -> bf16 (blocks 0..1023), transpose-cast 4 weights (1024..2047),
// zero vsp (block 2048)
// ---------------------------------------------------------------------------
__global__ __launch_bounds__(256) void prep(const float* __restrict__ x,
                                            const float* __restrict__ Wq,
                                            const float* __restrict__ Wk,
                                            const float* __restrict__ Wv,
                                            const float* __restrict__ Wo,
                                            bf16_t* __restrict__ xb,
                                            bf16_t* __restrict__ Wqt,
                                            bf16_t* __restrict__ Wkt,
                                            bf16_t* __restrict__ Wvt,
                                            bf16_t* __restrict__ Wot,
                                            float* __restrict__ vsp)
{
    __shared__ float T[64][65];
    const int blk = blockIdx.x;
    const int tid = threadIdx.x;
    if (blk < 1024) {
#pragma unroll
        for (int u = 0; u < 4; ++u) {
            const int g = blk * 1024 + u * 256 + tid;
            const float4 v = ((const float4*)x)[g];
            bf16x4 o;
            o[0] = (bf16_t)v.x; o[1] = (bf16_t)v.y;
            o[2] = (bf16_t)v.z; o[3] = (bf16_t)v.w;
            *(bf16x4*)&xb[(size_t)g * 4] = o;
        }
    } else if (blk < 2048) {
        const int rem = blk - 1024;
        const int wsel = rem >> 8, t = rem & 255;
        const float* src = (wsel == 0) ? Wq : (wsel == 1) ? Wk : (wsel == 2) ? Wv : Wo;
        bf16_t* dst = (wsel == 0) ? Wqt : (wsel == 1) ? Wkt : (wsel == 2) ? Wvt : Wot;
        const int k0 = (t >> 4) * 64, n0 = (t & 15) * 64;
        const int rr = tid >> 4, c4 = (tid & 15) * 4;
#pragma unroll
        for (int u = 0; u < 4; ++u) {
            const float4 v = *(const float4*)&src[(size_t)(k0 + u * 16 + rr) * 1024 + n0 + c4];
            T[u * 16 + rr][c4 + 0] = v.x; T[u * 16 + rr][c4 + 1] = v.y;
            T[u * 16 + rr][c4 + 2] = v.z; T[u * 16 + rr][c4 + 3] = v.w;
        }
        __syncthreads();
#pragma unroll
        for (int u = 0; u < 4; ++u) {
            bf16x4 o;
#pragma unroll
            for (int e = 0; e < 4; ++e) o[e] = (bf16_t)T[c4 + e][u * 16 + rr];
            *(bf16x4*)&dst[(size_t)(n0 + u * 16 + rr) * 1024 + k0 + c4] = o;
        }
    } else {
#pragma unroll
        for (int u = 0; u < 8; ++u) vsp[u * 256 + tid] = 0.f;
    }
}

// ---------------------------------------------------------------------------
// bf16 MFMA GEMM, tri-buffered pipeline: 2 K-tiles in flight, vmcnt(4)
// retires only the older tile (4 glds/wave/tile) so the newer stays flying
// across the barrier. Buffer for tile t+2 was last read computing t-1,
// which all waves finished before this barrier.
// ---------------------------------------------------------------------------
template <int MODE>
__device__ __forceinline__ void mfma_gemm_body(const bf16_t* __restrict__ A,
                                               const bf16_t* __restrict__ Bt,
                                               void* __restrict__ dst,
                                               float* __restrict__ vsum_out,
                                               int m0, int n0)
{
    __shared__ bf16_t As[12288];  // 3 x [128][32]
    __shared__ bf16_t Bs[12288];

    const int tid = threadIdx.x;
    const int lane = tid & 63, wid = tid >> 6;
    const int l15 = lane & 15, quad = lane >> 4;
    const int wm = (wid & 1) * 64, wn = (wid >> 1) * 64;

    const int srow = wid * 32 + (lane >> 2);
    const int scg8 = (lane & 3) * 8;
    const bf16_t* Ag0 = A  + (size_t)(m0 + srow) * 1024 + scg8;
    const bf16_t* Ag1 = A  + (size_t)(m0 + srow + 16) * 1024 + scg8;
    const bf16_t* Bg0 = Bt + (size_t)(n0 + srow) * 1024 + scg8;
    const bf16_t* Bg1 = Bt + (size_t)(n0 + srow + 16) * 1024 + scg8;

    f32x4 acc[4][4];
#pragma unroll
    for (int i = 0; i < 4; ++i)
#pragma unroll
        for (int j = 0; j < 4; ++j) acc[i][j] = (f32x4){0.f, 0.f, 0.f, 0.f};

    // prologue: tiles 0,1 into buffers 0,1
#pragma unroll
    for (int p = 0; p < 2; ++p) {
        const int k0 = p * 32;
        gl2lds16(Ag0 + k0, As + p * 4096 + (wid * 2 + 0) * 512);
        gl2lds16(Ag1 + k0, As + p * 4096 + (wid * 2 + 1) * 512);
        gl2lds16(Bg0 + k0, Bs + p * 4096 + (wid * 2 + 0) * 512);
        gl2lds16(Bg1 + k0, Bs + p * 4096 + (wid * 2 + 1) * 512);
    }

    int cbuf = 0, sbuf = 2;
    for (int it = 0; it < 32; ++it) {
        if (it + 2 < 32) WAIT_VM4(); else WAIT_VM0();  // current tile landed
        BARRIER();
        if (it + 2 < 32) {
            const int k0 = (it + 2) * 32;
            gl2lds16(Ag0 + k0, As + sbuf * 4096 + (wid * 2 + 0) * 512);
            gl2lds16(Ag1 + k0, As + sbuf * 4096 + (wid * 2 + 1) * 512);
            gl2lds16(Bg0 + k0, Bs + sbuf * 4096 + (wid * 2 + 0) * 512);
            gl2lds16(Bg1 + k0, Bs + sbuf * 4096 + (wid * 2 + 1) * 512);
            sbuf = (sbuf == 2) ? 0 : sbuf + 1;
        }
        bf16x8 af[4], bfr[4];
#pragma unroll
        for (int mt = 0; mt < 4; ++mt)
            af[mt] = *(const bf16x8*)&As[cbuf * 4096 + (wm + mt * 16 + l15) * 32 + quad * 8];
#pragma unroll
        for (int nt = 0; nt < 4; ++nt)
            bfr[nt] = *(const bf16x8*)&Bs[cbuf * 4096 + (wn + nt * 16 + l15) * 32 + quad * 8];
#pragma unroll
        for (int mt = 0; mt < 4; ++mt)
#pragma unroll
            for (int nt = 0; nt < 4; ++nt)
                acc[mt][nt] = MFMA_B16(bfr[nt], af[mt], acc[mt][nt]);  // lane=m, regs=n
        cbuf = (cbuf == 2) ? 0 : cbuf + 1;
    }

#pragma unroll
    for (int mt = 0; mt < 4; ++mt) {
        const int m = m0 + wm + mt * 16 + l15;
#pragma unroll
        for (int nt = 0; nt < 4; ++nt) {
            const int nb = n0 + wn + nt * 16 + quad * 4;
            if (MODE == 0) {
                *(f32x4*)&((float*)dst)[(size_t)m * 1024 + nb] = acc[mt][nt];
            } else {
                const int bb = m >> 11, s = m & 2047;
                const int hh = nb >> 6, d = nb & 63;
                bf16x4 o;
#pragma unroll
                for (int u = 0; u < 4; ++u) o[u] = (bf16_t)acc[mt][nt][u];
                *(bf16x4*)&((bf16_t*)dst)[((size_t)(bb * 16 + hh) * 2048 + s) * 64 + d] = o;
            }
        }
    }

    if (MODE == 1 && vsum_out != nullptr) {
        const int bb = m0 >> 11;
#pragma unroll
        for (int nt = 0; nt < 4; ++nt) {
            f32x4 p = acc[0][nt];
#pragma unroll
            for (int mt = 1; mt < 4; ++mt) {
                p[0] += acc[mt][nt][0]; p[1] += acc[mt][nt][1];
                p[2] += acc[mt][nt][2]; p[3] += acc[mt][nt][3];
            }
#pragma unroll
            for (int st = 1; st < 16; st <<= 1) {
                p[0] += __shfl_xor(p[0], st);
                p[1] += __shfl_xor(p[1], st);
                p[2] += __shfl_xor(p[2], st);
                p[3] += __shfl_xor(p[3], st);
            }
            if (l15 == 0) {
                const int nI = n0 + wn + nt * 16 + quad * 4;
                float* vp = &vsum_out[(bb * 16 + (nI >> 6)) * 64 + (nI & 63)];
                atomicAdd(vp + 0, p[0]);
                atomicAdd(vp + 1, p[1]);
                atomicAdd(vp + 2, p[2]);
                atomicAdd(vp + 3, p[3]);
            }
        }
    }
}

__global__ __launch_bounds__(256) void gemm_qkv_mfma(const bf16_t* __restrict__ xb,
                                                     const bf16_t* __restrict__ Wqt,
                                                     const bf16_t* __restrict__ Wkt,
                                                     const bf16_t* __restrict__ Wvt,
                                                     bf16_t* Qh, bf16_t* Kh, bf16_t* Vh,
                                                     float* vsp)
{
    const bf16_t* Bt = (blockIdx.z == 0) ? Wqt : (blockIdx.z == 1) ? Wkt : Wvt;
    bf16_t* dst = (blockIdx.z == 0) ? Qh : (blockIdx.z == 1) ? Kh : Vh;
    float* vs = (blockIdx.z == 2) ? vsp : nullptr;
    mfma_gemm_body<1>(xb, Bt, dst, vs, blockIdx.y * 128, blockIdx.x * 128);
}

__global__ __launch_bounds__(256) void gemm_out_mfma(const bf16_t* __restrict__ attn,
                                                     const bf16_t* __restrict__ Wot,
                                                     float* __restrict__ out)
{
    mfma_gemm_body<0>(attn, Wot, out, nullptr, blockIdx.y * 128, blockIdx.x * 128);
}

// ---------------------------------------------------------------------------
// Fused rowmax + band attention, v4.
// 512 blocks XCD-swizzled; block = 128 q-rows. NO register cap (occupancy is
// grid/LDS-limited at 2 blocks/CU; the r7 (256,4) cap caused spills).
// Phase 1: rowmax over 16 chunks of 128 j, TRI-buffered (2 chunks in flight,
// vmcnt(4) retires only the older; 4 glds/wave/chunk). Q in its own
// persistent LDS region; fragments hoisted once (dual-use in both phases).
// Phase 2: 6x64-j band chunks, __syncthreads flow (unchanged, verified).
// ---------------------------------------------------------------------------
__global__ __launch_bounds__(256) void attn_fused(const bf16_t* __restrict__ Qh,
                                                  const bf16_t* __restrict__ Kh,
                                                  const bf16_t* __restrict__ Vh,
                                                  const float* __restrict__ vsp,
                                                  bf16_t* __restrict__ attn)
{
    __shared__ bf16_t Qs[8192];     // [2 half][128][32], persistent
    __shared__ bf16_t Kp[24576];    // phase1: 3 x [2 half][128][32]; phase2 union
    __shared__ float msh[4][8][16];
    float (*zsh)[32] = (float(*)[32])msh;

    bf16_t* Ks2 = Kp;               // [2][64][32]  (4096)
    bf16_t* Vt  = Kp + 4096;        // [64][72]     (4608) [d][j]
    bf16_t* Ws  = Kp + 8704;        // [128][72]    (9216) [i][j]

    const int tid = threadIdx.x;
    const int lane = tid & 63, wid = tid >> 6;
    const int l15 = lane & 15, quad = lane >> 4;

    const int f = blockIdx.x;
    const int seq = f >> 3;
    const int bh = (f & 7) + 8 * (seq >> 4);   // XCD-locality
    const int i0 = (seq & 15) * 128;
    const int b = bh >> 4, h = bh & 15;
    const bf16_t* Qb = Qh + (size_t)bh * 131072;
    const bf16_t* Kb = Kh + (size_t)bh * 131072;
    const bf16_t* Vb = Vh + (size_t)bh * 131072;

    // ---- prologue: stage Q, then K chunks 0,1 (12 glds outstanding) ----
#pragma unroll
    for (int c = 0; c < 4; ++c) {
        const int g = wid * 4 + c;
        const int half = g >> 3;
        const int row = (g & 7) * 16 + (lane >> 2);
        gl2lds16(Qb + (size_t)(i0 + row) * 64 + half * 32 + (lane & 3) * 8,
                 Qs + g * 512);
    }
#pragma unroll
    for (int p = 0; p < 2; ++p) {
#pragma unroll
        for (int c = 0; c < 4; ++c) {
            const int g = wid * 4 + c;
            const int half = g >> 3;
            const int row = (g & 7) * 16 + (lane >> 2);
            gl2lds16(Kb + (size_t)(p * 128 + row) * 64 + half * 32 + (lane & 3) * 8,
                     Kp + p * 8192 + g * 512);
        }
    }
    WAIT_VM8();   // Q's 4 landed; K0/K1 still flying
    BARRIER();

    // hoist Q fragments (Qs never overwritten -> no extra fence needed)
    bf16x8 af[8][2];
#pragma unroll
    for (int mt = 0; mt < 8; ++mt)
#pragma unroll
        for (int ks = 0; ks < 2; ++ks)
            af[mt][ks] = *(const bf16x8*)&Qs[ks * 4096 + (mt * 16 + l15) * 32 + quad * 8];

    // ---- phase 1: rowmax, 16 chunks of 128 j, tri-buffer pipeline ----
    float rmax[8];
#pragma unroll
    for (int mt = 0; mt < 8; ++mt) rmax[mt] = -3.0e38f;

    int cbuf = 0, sbuf = 2;
    for (int jc = 0; jc < 16; ++jc) {
        if (jc + 2 < 16) WAIT_VM4(); else WAIT_VM0();  // chunk jc landed
        BARRIER();
        if (jc + 2 < 16) {
            bf16_t* nb = Kp + sbuf * 8192;
#pragma unroll
            for (int c = 0; c < 4; ++c) {
                const int g = wid * 4 + c;
                const int half = g >> 3;
                const int row = (g & 7) * 16 + (lane >> 2);
                gl2lds16(Kb + (size_t)((jc + 2) * 128 + row) * 64 + half * 32 + (lane & 3) * 8,
                         nb + g * 512);
            }
            sbuf = (sbuf == 2) ? 0 : sbuf + 1;
        }
        const bf16_t* cb = Kp + cbuf * 8192;
#pragma unroll
        for (int ntl = 0; ntl < 2; ++ntl) {
            const int jt = wid * 2 + ntl;
            const bf16x8 b0 = *(const bf16x8*)&cb[(jt * 16 + l15) * 32 + quad * 8];
            const bf16x8 b1 = *(const bf16x8*)&cb[4096 + (jt * 16 + l15) * 32 + quad * 8];
#pragma unroll
            for (int mt = 0; mt < 8; ++mt) {
                f32x4 t = (f32x4){0.f, 0.f, 0.f, 0.f};
                t = MFMA_B16(b0, af[mt][0], t);   // lane = i, regs = j
                t = MFMA_B16(b1, af[mt][1], t);
                rmax[mt] = fmaxf(rmax[mt], fmaxf(fmaxf(t[0], t[1]), fmaxf(t[2], t[3])));
            }
        }
        cbuf = (cbuf == 2) ? 0 : cbuf + 1;
    }
#pragma unroll
    for (int mt = 0; mt < 8; ++mt) {
        float v = rmax[mt];
        v = fmaxf(v, __shfl_xor(v, 16));
        v = fmaxf(v, __shfl_xor(v, 32));
        if (quad == 0) msh[wid][mt][l15] = v;
    }
    __syncthreads();  // msh visible; phase-1 Kp reads done

    float mreg[2][4];
#pragma unroll
    for (int t = 0; t < 2; ++t)
#pragma unroll
        for (int r = 0; r < 4; ++r) {
            const int mt = wid * 2 + t;
            const int il = quad * 4 + r;
            mreg[t][r] = SCALE * fmaxf(fmaxf(msh[0][mt][il], msh[1][mt][il]),
                                       fmaxf(msh[2][mt][il], msh[3][mt][il]));
        }

    f32x4 vsd4[4];
#pragma unroll
    for (int dt = 0; dt < 4; ++dt)
        vsd4[dt] = *(const f32x4*)&vsp[bh * 64 + dt * 16 + quad * 4];

    f32x4 accO[2][4];
#pragma unroll
    for (int t = 0; t < 2; ++t)
#pragma unroll
        for (int dt = 0; dt < 4; ++dt) accO[t][dt] = (f32x4){0.f, 0.f, 0.f, 0.f};
    float zp[2][4] = {{0.f, 0.f, 0.f, 0.f}, {0.f, 0.f, 0.f, 0.f}};

    // ---- phase 2: 6 band chunks of 64 j ----
    for (int cb2 = 0; cb2 < 6; ++cb2) {
        const int jb = i0 - 128 + cb2 * 64;
        if (jb < 0 || jb >= S_) continue;  // block-uniform

        __syncthreads();
#pragma unroll
        for (int c = 0; c < 2; ++c) {
            const int g = wid * 2 + c;
            const int half = g >> 2;
            const int row = (g & 3) * 16 + (lane >> 2);
            gl2lds16(Kb + (size_t)(jb + row) * 64 + half * 32 + (lane & 3) * 8,
                     Ks2 + g * 512);
        }
        {
            const bf16x8 v0 = *(const bf16x8*)&Vb[(size_t)(jb + lane) * 64 + wid * 16];
            const bf16x8 v1 = *(const bf16x8*)&Vb[(size_t)(jb + lane) * 64 + wid * 16 + 8];
#pragma unroll
            for (int e = 0; e < 8; ++e) {
                Vt[(wid * 16 + e) * 72 + lane] = v0[e];
                Vt[(wid * 16 + 8 + e) * 72 + lane] = v1[e];
            }
        }
        __syncthreads();

#pragma unroll
        for (int t = 0; t < 2; ++t) {
            const int mt = wid * 2 + t;
#pragma unroll
            for (int jt4 = 0; jt4 < 4; ++jt4) {
                const bf16x8 k0 = *(const bf16x8*)&Ks2[(jt4 * 16 + l15) * 32 + quad * 8];
                const bf16x8 k1 = *(const bf16x8*)&Ks2[2048 + (jt4 * 16 + l15) * 32 + quad * 8];
                f32x4 sc = (f32x4){0.f, 0.f, 0.f, 0.f};
                sc = MFMA_B16(af[mt][0], k0, sc);   // lane = j, regs = i
                sc = MFMA_B16(af[mt][1], k1, sc);
#pragma unroll
                for (int r = 0; r < 4; ++r) {
                    const int ig = i0 + mt * 16 + quad * 4 + r;
                    const int jg = jb + jt4 * 16 + l15;
                    const int dd = jg - ig;
                    const bool ok = (dd >= -128) && (dd <= 127);
                    const float e1 = __expf(sc[r] * SCALE - mreg[t][r]);
                    const float wv = ok ? (__expf(e1) - 1.0f) : 0.0f;
                    const bf16_t wb = (bf16_t)wv;
                    zp[t][r] += (float)wb;
                    Ws[(mt * 16 + quad * 4 + r) * 72 + jt4 * 16 + l15] = wb;
                }
            }
        }
        __syncthreads();

#pragma unroll
        for (int ks = 0; ks < 2; ++ks) {
            bf16x8 bv[4];
#pragma unroll
            for (int dt = 0; dt < 4; ++dt)
                bv[dt] = *(const bf16x8*)&Vt[(dt * 16 + l15) * 72 + ks * 32 + quad * 8];
#pragma unroll
            for (int t = 0; t < 2; ++t) {
                const int mt = wid * 2 + t;
                const bf16x8 aw = *(const bf16x8*)&Ws[(mt * 16 + l15) * 72 + ks * 32 + quad * 8];
#pragma unroll
                for (int dt = 0; dt < 4; ++dt)
                    accO[t][dt] = MFMA_B16(bv[dt], aw, accO[t][dt]);
            }
        }
    }

    // Z reduce + redistribute (zsh aliases msh; msh reads finished long ago)
#pragma unroll
    for (int t = 0; t < 2; ++t)
#pragma unroll
        for (int r = 0; r < 4; ++r) {
            float z = zp[t][r];
            z += __shfl_xor(z, 1);
            z += __shfl_xor(z, 2);
            z += __shfl_xor(z, 4);
            z += __shfl_xor(z, 8);
            if (l15 == 0) zsh[wid][t * 16 + quad * 4 + r] = z + (float)S_;
        }
    __syncthreads();

#pragma unroll
    for (int t = 0; t < 2; ++t) {
        const float rz = 1.0f / zsh[wid][t * 16 + l15];
        const int irow = i0 + (wid * 2 + t) * 16 + l15;
#pragma unroll
        for (int dt = 0; dt < 4; ++dt) {
            bf16x4 o;
#pragma unroll
            for (int r = 0; r < 4; ++r)
                o[r] = (bf16_t)((accO[t][dt][r] + vsd4[dt][r]) * rz);
            *(bf16x4*)&attn[(size_t)(b * S_ + irow) * 1024 + h * 64 + dt * 16 + quad * 4] = o;
        }
    }
}

// ---------------------------------------------------------------------------
// Launch: 4 kernels
// ---------------------------------------------------------------------------
extern "C" void kernel_launch(void* const* d_in, const int* in_sizes, int n_in,
                              void* d_out, int out_size, void* d_ws, size_t ws_size,
                              hipStream_t stream)
{
    const float* x  = (const float*)d_in[0];
    const float* Wq = (const float*)d_in[1];
    const float* Wk = (const float*)d_in[2];
    const float* Wv = (const float*)d_in[3];
    const float* Wo = (const float*)d_in[4];
    float* out = (float*)d_out;

    char* ws = (char*)d_ws;
    bf16_t* xb   = (bf16_t*)(ws + 0);
    bf16_t* Wqt  = (bf16_t*)(ws + 8388608);
    bf16_t* Wkt  = (bf16_t*)(ws + 10485760);
    bf16_t* Wvt  = (bf16_t*)(ws + 12582912);
    bf16_t* Wot  = (bf16_t*)(ws + 14680064);
    bf16_t* Qh   = (bf16_t*)(ws + 16777216);   // [bh][s][64]
    bf16_t* Kh   = (bf16_t*)(ws + 25165824);
    bf16_t* Vh   = (bf16_t*)(ws + 33554432);
    bf16_t* attn = (bf16_t*)(ws + 41943040);   // [m][1024]
    float*  vsp  = (float*)(ws + 50331648);    // [bh][64] f32, zeroed by prep

    prep<<<2049, 256, 0, stream>>>(x, Wq, Wk, Wv, Wo, xb, Wqt, Wkt, Wvt, Wot, vsp);
    gemm_qkv_mfma<<<dim3(8, 32, 3), 256, 0, stream>>>(xb, Wqt, Wkt, Wvt, Qh, Kh, Vh, vsp);
    attn_fused<<<512, 256, 0, stream>>>(Qh, Kh, Vh, vsp, attn);
    gemm_out_mfma<<<dim3(8, 32), 256, 0, stream>>>(attn, Wot, out);
}

// Round 10
// 187.937 us; speedup vs baseline: 1.1117x; 1.0109x over previous
//
#include <hip/hip_runtime.h>
#include <math.h>

typedef __bf16 bf16_t;
typedef bf16_t bf16x8 __attribute__((ext_vector_type(8)));
typedef bf16_t bf16x4 __attribute__((ext_vector_type(4)));
typedef float f32x4 __attribute__((ext_vector_type(4)));

constexpr int S_ = 2048;
constexpr float SCALE = 0.125f;  // 1/sqrt(64)

#define MFMA_B16(a, b, c) __builtin_amdgcn_mfma_f32_16x16x32_bf16(a, b, c, 0, 0, 0)

// s_waitcnt immediates (gfx9 enc): [3:0]=vmcnt_lo, [6:4]=expcnt, [12:8]=lgkmcnt
#define WAIT_VM0() __builtin_amdgcn_s_waitcnt(0x0F70)
#define WAIT_VM4() __builtin_amdgcn_s_waitcnt(0x0F74)
#define BARRIER()  __builtin_amdgcn_s_barrier()

typedef __attribute__((address_space(1))) const void* as1_cvp;
typedef __attribute__((address_space(3))) void* as3_vp;

__device__ __forceinline__ void gl2lds16(const void* g, void* l)
{
    __builtin_amdgcn_global_load_lds((as1_cvp)g, (as3_vp)l, 16, 0, 0);
}

// ---------------------------------------------------------------------------
// prep: cast x -> bf16 (blocks 0..1023), transpose-cast 4 weights (1024..2047),
// zero vsp (block 2048)
// ---------------------------------------------------------------------------
__global__ __launch_bounds__(256) void prep(const float* __restrict__ x,
                                            const float* __restrict__ Wq,
                                            const float* __restrict__ Wk,
                                            const float* __restrict__ Wv,
                                            const float* __restrict__ Wo,
                                            bf16_t* __restrict__ xb,
                                            bf16_t* __restrict__ Wqt,
                                            bf16_t* __restrict__ Wkt,
                                            bf16_t* __restrict__ Wvt,
                                            bf16_t* __restrict__ Wot,
                                            float* __restrict__ vsp)
{
    __shared__ float T[64][65];
    const int blk = blockIdx.x;
    const int tid = threadIdx.x;
    if (blk < 1024) {
#pragma unroll
        for (int u = 0; u < 4; ++u) {
            const int g = blk * 1024 + u * 256 + tid;
            const float4 v = ((const float4*)x)[g];
            bf16x4 o;
            o[0] = (bf16_t)v.x; o[1] = (bf16_t)v.y;
            o[2] = (bf16_t)v.z; o[3] = (bf16_t)v.w;
            *(bf16x4*)&xb[(size_t)g * 4] = o;
        }
    } else if (blk < 2048) {
        const int rem = blk - 1024;
        const int wsel = rem >> 8, t = rem & 255;
        const float* src = (wsel == 0) ? Wq : (wsel == 1) ? Wk : (wsel == 2) ? Wv : Wo;
        bf16_t* dst = (wsel == 0) ? Wqt : (wsel == 1) ? Wkt : (wsel == 2) ? Wvt : Wot;
        const int k0 = (t >> 4) * 64, n0 = (t & 15) * 64;
        const int rr = tid >> 4, c4 = (tid & 15) * 4;
#pragma unroll
        for (int u = 0; u < 4; ++u) {
            const float4 v = *(const float4*)&src[(size_t)(k0 + u * 16 + rr) * 1024 + n0 + c4];
            T[u * 16 + rr][c4 + 0] = v.x; T[u * 16 + rr][c4 + 1] = v.y;
            T[u * 16 + rr][c4 + 2] = v.z; T[u * 16 + rr][c4 + 3] = v.w;
        }
        __syncthreads();
#pragma unroll
        for (int u = 0; u < 4; ++u) {
            bf16x4 o;
#pragma unroll
            for (int e = 0; e < 4; ++e) o[e] = (bf16_t)T[c4 + e][u * 16 + rr];
            *(bf16x4*)&dst[(size_t)(n0 + u * 16 + rr) * 1024 + k0 + c4] = o;
        }
    } else {
#pragma unroll
        for (int u = 0; u < 8; ++u) vsp[u * 256 + tid] = 0.f;
    }
}

// ---------------------------------------------------------------------------
// bf16 MFMA GEMM, tri-buffered, fully unrolled K-loop (static buffer indices).
// 2 tiles in flight, vmcnt(4) retires only the older.
// ---------------------------------------------------------------------------
template <int MODE>
__device__ __forceinline__ void mfma_gemm_body(const bf16_t* __restrict__ A,
                                               const bf16_t* __restrict__ Bt,
                                               void* __restrict__ dst,
                                               float* __restrict__ vsum_out,
                                               int m0, int n0)
{
    __shared__ bf16_t As[12288];  // 3 x [128][32]
    __shared__ bf16_t Bs[12288];

    const int tid = threadIdx.x;
    const int lane = tid & 63, wid = tid >> 6;
    const int l15 = lane & 15, quad = lane >> 4;
    const int wm = (wid & 1) * 64, wn = (wid >> 1) * 64;

    const int srow = wid * 32 + (lane >> 2);
    const int scg8 = (lane & 3) * 8;
    const bf16_t* Ag0 = A  + (size_t)(m0 + srow) * 1024 + scg8;
    const bf16_t* Ag1 = A  + (size_t)(m0 + srow + 16) * 1024 + scg8;
    const bf16_t* Bg0 = Bt + (size_t)(n0 + srow) * 1024 + scg8;
    const bf16_t* Bg1 = Bt + (size_t)(n0 + srow + 16) * 1024 + scg8;

    f32x4 acc[4][4];
#pragma unroll
    for (int i = 0; i < 4; ++i)
#pragma unroll
        for (int j = 0; j < 4; ++j) acc[i][j] = (f32x4){0.f, 0.f, 0.f, 0.f};

    // prologue: tiles 0,1 into buffers 0,1
#pragma unroll
    for (int p = 0; p < 2; ++p) {
        const int k0 = p * 32;
        gl2lds16(Ag0 + k0, As + p * 4096 + (wid * 2 + 0) * 512);
        gl2lds16(Ag1 + k0, As + p * 4096 + (wid * 2 + 1) * 512);
        gl2lds16(Bg0 + k0, Bs + p * 4096 + (wid * 2 + 0) * 512);
        gl2lds16(Bg1 + k0, Bs + p * 4096 + (wid * 2 + 1) * 512);
    }

#pragma unroll
    for (int it = 0; it < 32; ++it) {
        if (it < 30) WAIT_VM4(); else WAIT_VM0();
        BARRIER();
        if (it < 30) {
            const int k0 = (it + 2) * 32;
            const int sb = (it + 2) % 3;          // compile-time after unroll
            gl2lds16(Ag0 + k0, As + sb * 4096 + (wid * 2 + 0) * 512);
            gl2lds16(Ag1 + k0, As + sb * 4096 + (wid * 2 + 1) * 512);
            gl2lds16(Bg0 + k0, Bs + sb * 4096 + (wid * 2 + 0) * 512);
            gl2lds16(Bg1 + k0, Bs + sb * 4096 + (wid * 2 + 1) * 512);
        }
        const int cb = it % 3;                    // compile-time after unroll
        bf16x8 af[4], bfr[4];
#pragma unroll
        for (int mt = 0; mt < 4; ++mt)
            af[mt] = *(const bf16x8*)&As[cb * 4096 + (wm + mt * 16 + l15) * 32 + quad * 8];
#pragma unroll
        for (int nt = 0; nt < 4; ++nt)
            bfr[nt] = *(const bf16x8*)&Bs[cb * 4096 + (wn + nt * 16 + l15) * 32 + quad * 8];
#pragma unroll
        for (int mt = 0; mt < 4; ++mt)
#pragma unroll
            for (int nt = 0; nt < 4; ++nt)
                acc[mt][nt] = MFMA_B16(bfr[nt], af[mt], acc[mt][nt]);  // lane=m, regs=n
    }

#pragma unroll
    for (int mt = 0; mt < 4; ++mt) {
        const int m = m0 + wm + mt * 16 + l15;
#pragma unroll
        for (int nt = 0; nt < 4; ++nt) {
            const int nb = n0 + wn + nt * 16 + quad * 4;
            if (MODE == 0) {
                *(f32x4*)&((float*)dst)[(size_t)m * 1024 + nb] = acc[mt][nt];
            } else {
                const int bb = m >> 11, s = m & 2047;
                const int hh = nb >> 6, d = nb & 63;
                bf16x4 o;
#pragma unroll
                for (int u = 0; u < 4; ++u) o[u] = (bf16_t)acc[mt][nt][u];
                *(bf16x4*)&((bf16_t*)dst)[((size_t)(bb * 16 + hh) * 2048 + s) * 64 + d] = o;
            }
        }
    }

    if (MODE == 1 && vsum_out != nullptr) {
        const int bb = m0 >> 11;
#pragma unroll
        for (int nt = 0; nt < 4; ++nt) {
            f32x4 p = acc[0][nt];
#pragma unroll
            for (int mt = 1; mt < 4; ++mt) {
                p[0] += acc[mt][nt][0]; p[1] += acc[mt][nt][1];
                p[2] += acc[mt][nt][2]; p[3] += acc[mt][nt][3];
            }
#pragma unroll
            for (int st = 1; st < 16; st <<= 1) {
                p[0] += __shfl_xor(p[0], st);
                p[1] += __shfl_xor(p[1], st);
                p[2] += __shfl_xor(p[2], st);
                p[3] += __shfl_xor(p[3], st);
            }
            if (l15 == 0) {
                const int nI = n0 + wn + nt * 16 + quad * 4;
                float* vp = &vsum_out[(bb * 16 + (nI >> 6)) * 64 + (nI & 63)];
                atomicAdd(vp + 0, p[0]);
                atomicAdd(vp + 1, p[1]);
                atomicAdd(vp + 2, p[2]);
                atomicAdd(vp + 3, p[3]);
            }
        }
    }
}

__global__ __launch_bounds__(256) void gemm_qkv_mfma(const bf16_t* __restrict__ xb,
                                                     const bf16_t* __restrict__ Wqt,
                                                     const bf16_t* __restrict__ Wkt,
                                                     const bf16_t* __restrict__ Wvt,
                                                     bf16_t* Qh, bf16_t* Kh, bf16_t* Vh,
                                                     float* vsp)
{
    const bf16_t* Bt = (blockIdx.z == 0) ? Wqt : (blockIdx.z == 1) ? Wkt : Wvt;
    bf16_t* dst = (blockIdx.z == 0) ? Qh : (blockIdx.z == 1) ? Kh : Vh;
    float* vs = (blockIdx.z == 2) ? vsp : nullptr;
    mfma_gemm_body<1>(xb, Bt, dst, vs, blockIdx.y * 128, blockIdx.x * 128);
}

__global__ __launch_bounds__(256) void gemm_out_mfma(const bf16_t* __restrict__ attn,
                                                     const bf16_t* __restrict__ Wot,
                                                     float* __restrict__ out)
{
    mfma_gemm_body<0>(attn, Wot, out, nullptr, blockIdx.y * 128, blockIdx.x * 128);
}

// ---------------------------------------------------------------------------
// rowmax: mrow[bh][i] = SCALE * max_j (q_i . k_j). 512 blocks XCD-swizzled,
// block = 128 q-rows, 16 chunks of 128 j; j-tiles partitioned across waves,
// so each wave's running max is PARTIAL over j. Cross-wave combine via LDS
// (msh) before the global write — r9's missing step (was a write race).
// ---------------------------------------------------------------------------
__global__ __launch_bounds__(256) void rowmax_k(const bf16_t* __restrict__ Qh,
                                                const bf16_t* __restrict__ Kh,
                                                float* __restrict__ mrow)
{
    __shared__ bf16_t Qs[8192];  // [2 half][128][32]
    __shared__ bf16_t Ks[8192];  // [2 half][128][32]
    __shared__ float msh[4][8][16];  // [wave][i-tile][i-within]

    const int tid = threadIdx.x;
    const int lane = tid & 63, wid = tid >> 6;
    const int l15 = lane & 15, quad = lane >> 4;

    const int f = blockIdx.x;
    const int seq = f >> 3;
    const int bh = (f & 7) + 8 * (seq >> 4);   // XCD-locality
    const int i0 = (seq & 15) * 128;
    const bf16_t* Qb = Qh + (size_t)bh * 131072;
    const bf16_t* Kb = Kh + (size_t)bh * 131072;

    // stage Q [2][128][32] (16 granules, 4/wave)
#pragma unroll
    for (int c = 0; c < 4; ++c) {
        const int g = wid * 4 + c;
        const int half = g >> 3;
        const int row = (g & 7) * 16 + (lane >> 2);
        gl2lds16(Qb + (size_t)(i0 + row) * 64 + half * 32 + (lane & 3) * 8,
                 Qs + g * 512);
    }
    __syncthreads();

    bf16x8 af[8][2];
#pragma unroll
    for (int mt = 0; mt < 8; ++mt)
#pragma unroll
        for (int ks = 0; ks < 2; ++ks)
            af[mt][ks] = *(const bf16x8*)&Qs[ks * 4096 + (mt * 16 + l15) * 32 + quad * 8];

    f32x4 vm[8];
#pragma unroll
    for (int mt = 0; mt < 8; ++mt)
        vm[mt] = (f32x4){-3.0e38f, -3.0e38f, -3.0e38f, -3.0e38f};

    for (int jc = 0; jc < 16; ++jc) {
        __syncthreads();  // previous chunk's readers done
#pragma unroll
        for (int c = 0; c < 4; ++c) {
            const int g = wid * 4 + c;
            const int half = g >> 3;
            const int row = (g & 7) * 16 + (lane >> 2);
            gl2lds16(Kb + (size_t)(jc * 128 + row) * 64 + half * 32 + (lane & 3) * 8,
                     Ks + g * 512);
        }
        __syncthreads();  // drains vmcnt -> K visible

#pragma unroll
        for (int ntl = 0; ntl < 2; ++ntl) {
            const int jt = wid * 2 + ntl;   // wave's j-tiles (PARTIAL over j)
            const bf16x8 b0 = *(const bf16x8*)&Ks[(jt * 16 + l15) * 32 + quad * 8];
            const bf16x8 b1 = *(const bf16x8*)&Ks[4096 + (jt * 16 + l15) * 32 + quad * 8];
#pragma unroll
            for (int mt = 0; mt < 8; ++mt) {
                f32x4 t = (f32x4){0.f, 0.f, 0.f, 0.f};
                t = MFMA_B16(b0, af[mt][0], t);   // lane = i, regs = j
                t = MFMA_B16(b1, af[mt][1], t);
                vm[mt][0] = fmaxf(vm[mt][0], t[0]);
                vm[mt][1] = fmaxf(vm[mt][1], t[1]);
                vm[mt][2] = fmaxf(vm[mt][2], t[2]);
                vm[mt][3] = fmaxf(vm[mt][3], t[3]);
            }
        }
    }

    // per-wave partial -> LDS
#pragma unroll
    for (int mt = 0; mt < 8; ++mt) {
        float v = fmaxf(fmaxf(vm[mt][0], vm[mt][1]), fmaxf(vm[mt][2], vm[mt][3]));
        v = fmaxf(v, __shfl_xor(v, 16));
        v = fmaxf(v, __shfl_xor(v, 32));
        if (quad == 0) msh[wid][mt][l15] = v;
    }
    __syncthreads();

    // cross-wave combine + write (threads 0..127, one per output row)
    if (tid < 128) {
        const int mt = tid >> 4, il = tid & 15;
        const float v = fmaxf(fmaxf(msh[0][mt][il], msh[1][mt][il]),
                              fmaxf(msh[2][mt][il], msh[3][mt][il]));
        mrow[(size_t)bh * S_ + i0 + mt * 16 + il] = v * SCALE;
    }
}

// ---------------------------------------------------------------------------
// band attention: 512 blocks XCD-swizzled, block = 128 q-rows, 6 chunks of
// 64 j. i-tiles partitioned across waves (each wave complete over j -> no
// cross-wave combine needed).
// out_i = (sum_band (e^t - 1) v_j + vsum) / (sum_band (e^t - 1) + S)
// ---------------------------------------------------------------------------
__global__ __launch_bounds__(256) void band_k(const bf16_t* __restrict__ Qh,
                                              const bf16_t* __restrict__ Kh,
                                              const bf16_t* __restrict__ Vh,
                                              const float* __restrict__ mrow,
                                              const float* __restrict__ vsp,
                                              bf16_t* __restrict__ attn)
{
    __shared__ bf16_t Qs[8192];   // [2 half][128][32]
    __shared__ bf16_t Ks2[4096];  // [2 half][64][32]
    __shared__ bf16_t Vt[4608];   // [64][72]  [d][j]
    __shared__ bf16_t Ws[9216];   // [128][72] [i][j]
    __shared__ float zsh[4][32];

    const int tid = threadIdx.x;
    const int lane = tid & 63, wid = tid >> 6;
    const int l15 = lane & 15, quad = lane >> 4;

    const int f = blockIdx.x;
    const int seq = f >> 3;
    const int bh = (f & 7) + 8 * (seq >> 4);
    const int i0 = (seq & 15) * 128;
    const int b = bh >> 4, h = bh & 15;
    const bf16_t* Qb = Qh + (size_t)bh * 131072;
    const bf16_t* Kb = Kh + (size_t)bh * 131072;
    const bf16_t* Vb = Vh + (size_t)bh * 131072;

#pragma unroll
    for (int c = 0; c < 4; ++c) {
        const int g = wid * 4 + c;
        const int half = g >> 3;
        const int row = (g & 7) * 16 + (lane >> 2);
        gl2lds16(Qb + (size_t)(i0 + row) * 64 + half * 32 + (lane & 3) * 8,
                 Qs + g * 512);
    }
    __syncthreads();

    // wave's 2 i-tiles only: aq[t][ks]
    bf16x8 aq[2][2];
#pragma unroll
    for (int t = 0; t < 2; ++t)
#pragma unroll
        for (int ks = 0; ks < 2; ++ks)
            aq[t][ks] = *(const bf16x8*)&Qs[ks * 4096 + ((wid * 2 + t) * 16 + l15) * 32 + quad * 8];

    float mreg[2][4];
#pragma unroll
    for (int t = 0; t < 2; ++t)
#pragma unroll
        for (int r = 0; r < 4; ++r)
            mreg[t][r] = mrow[(size_t)bh * S_ + i0 + (wid * 2 + t) * 16 + quad * 4 + r];

    f32x4 vsd4[4];
#pragma unroll
    for (int dt = 0; dt < 4; ++dt)
        vsd4[dt] = *(const f32x4*)&vsp[bh * 64 + dt * 16 + quad * 4];

    f32x4 accO[2][4];
#pragma unroll
    for (int t = 0; t < 2; ++t)
#pragma unroll
        for (int dt = 0; dt < 4; ++dt) accO[t][dt] = (f32x4){0.f, 0.f, 0.f, 0.f};
    float zp[2][4] = {{0.f, 0.f, 0.f, 0.f}, {0.f, 0.f, 0.f, 0.f}};

    for (int cb2 = 0; cb2 < 6; ++cb2) {
        const int jb = i0 - 128 + cb2 * 64;
        if (jb < 0 || jb >= S_) continue;  // block-uniform

        __syncthreads();
#pragma unroll
        for (int c = 0; c < 2; ++c) {
            const int g = wid * 2 + c;
            const int half = g >> 2;
            const int row = (g & 3) * 16 + (lane >> 2);
            gl2lds16(Kb + (size_t)(jb + row) * 64 + half * 32 + (lane & 3) * 8,
                     Ks2 + g * 512);
        }
        {
            const bf16x8 v0 = *(const bf16x8*)&Vb[(size_t)(jb + lane) * 64 + wid * 16];
            const bf16x8 v1 = *(const bf16x8*)&Vb[(size_t)(jb + lane) * 64 + wid * 16 + 8];
#pragma unroll
            for (int e = 0; e < 8; ++e) {
                Vt[(wid * 16 + e) * 72 + lane] = v0[e];
                Vt[(wid * 16 + 8 + e) * 72 + lane] = v1[e];
            }
        }
        __syncthreads();

#pragma unroll
        for (int t = 0; t < 2; ++t) {
            const int mt = wid * 2 + t;
#pragma unroll
            for (int jt4 = 0; jt4 < 4; ++jt4) {
                const bf16x8 k0 = *(const bf16x8*)&Ks2[(jt4 * 16 + l15) * 32 + quad * 8];
                const bf16x8 k1 = *(const bf16x8*)&Ks2[2048 + (jt4 * 16 + l15) * 32 + quad * 8];
                f32x4 sc = (f32x4){0.f, 0.f, 0.f, 0.f};
                sc = MFMA_B16(aq[t][0], k0, sc);   // lane = j, regs = i
                sc = MFMA_B16(aq[t][1], k1, sc);
#pragma unroll
                for (int r = 0; r < 4; ++r) {
                    const int ig = i0 + mt * 16 + quad * 4 + r;
                    const int jg = jb + jt4 * 16 + l15;
                    const int dd = jg - ig;
                    const bool ok = (dd >= -128) && (dd <= 127);
                    const float e1 = __expf(sc[r] * SCALE - mreg[t][r]);
                    const float wv = ok ? (__expf(e1) - 1.0f) : 0.0f;
                    const bf16_t wb = (bf16_t)wv;
                    zp[t][r] += (float)wb;
                    Ws[(mt * 16 + quad * 4 + r) * 72 + jt4 * 16 + l15] = wb;
                }
            }
        }
        __syncthreads();

#pragma unroll
        for (int ks = 0; ks < 2; ++ks) {
            bf16x8 bv[4];
#pragma unroll
            for (int dt = 0; dt < 4; ++dt)
                bv[dt] = *(const bf16x8*)&Vt[(dt * 16 + l15) * 72 + ks * 32 + quad * 8];
#pragma unroll
            for (int t = 0; t < 2; ++t) {
                const int mt = wid * 2 + t;
                const bf16x8 aw = *(const bf16x8*)&Ws[(mt * 16 + l15) * 72 + ks * 32 + quad * 8];
#pragma unroll
                for (int dt = 0; dt < 4; ++dt)
                    accO[t][dt] = MFMA_B16(bv[dt], aw, accO[t][dt]);  // lane=i, regs=d
            }
        }
    }

#pragma unroll
    for (int t = 0; t < 2; ++t)
#pragma unroll
        for (int r = 0; r < 4; ++r) {
            float z = zp[t][r];
            z += __shfl_xor(z, 1);
            z += __shfl_xor(z, 2);
            z += __shfl_xor(z, 4);
            z += __shfl_xor(z, 8);
            if (l15 == 0) zsh[wid][t * 16 + quad * 4 + r] = z + (float)S_;
        }
    __syncthreads();

#pragma unroll
    for (int t = 0; t < 2; ++t) {
        const float rz = 1.0f / zsh[wid][t * 16 + l15];
        const int irow = i0 + (wid * 2 + t) * 16 + l15;
#pragma unroll
        for (int dt = 0; dt < 4; ++dt) {
            bf16x4 o;
#pragma unroll
            for (int r = 0; r < 4; ++r)
                o[r] = (bf16_t)((accO[t][dt][r] + vsd4[dt][r]) * rz);
            *(bf16x4*)&attn[(size_t)(b * S_ + irow) * 1024 + h * 64 + dt * 16 + quad * 4] = o;
        }
    }
}

// ---------------------------------------------------------------------------
// Launch: 5 kernels
// ---------------------------------------------------------------------------
extern "C" void kernel_launch(void* const* d_in, const int* in_sizes, int n_in,
                              void* d_out, int out_size, void* d_ws, size_t ws_size,
                              hipStream_t stream)
{
    const float* x  = (const float*)d_in[0];
    const float* Wq = (const float*)d_in[1];
    const float* Wk = (const float*)d_in[2];
    const float* Wv = (const float*)d_in[3];
    const float* Wo = (const float*)d_in[4];
    float* out = (float*)d_out;

    char* ws = (char*)d_ws;
    bf16_t* xb   = (bf16_t*)(ws + 0);
    bf16_t* Wqt  = (bf16_t*)(ws + 8388608);
    bf16_t* Wkt  = (bf16_t*)(ws + 10485760);
    bf16_t* Wvt  = (bf16_t*)(ws + 12582912);
    bf16_t* Wot  = (bf16_t*)(ws + 14680064);
    bf16_t* Qh   = (bf16_t*)(ws + 16777216);   // [bh][s][64]
    bf16_t* Kh   = (bf16_t*)(ws + 25165824);
    bf16_t* Vh   = (bf16_t*)(ws + 33554432);
    bf16_t* attn = (bf16_t*)(ws + 41943040);   // [m][1024]
    float*  vsp  = (float*)(ws + 50331648);    // [bh][64] f32, zeroed by prep
    float*  mrow = (float*)(ws + 50339840);    // [bh][2048] f32

    prep<<<2049, 256, 0, stream>>>(x, Wq, Wk, Wv, Wo, xb, Wqt, Wkt, Wvt, Wot, vsp);
    gemm_qkv_mfma<<<dim3(8, 32, 3), 256, 0, stream>>>(xb, Wqt, Wkt, Wvt, Qh, Kh, Vh, vsp);
    rowmax_k<<<512, 256, 0, stream>>>(Qh, Kh, mrow);
    band_k<<<512, 256, 0, stream>>>(Qh, Kh, Vh, mrow, vsp, attn);
    gemm_out_mfma<<<dim3(8, 32), 256, 0, stream>>>(attn, Wot, out);
}